// Round 9
// baseline (174.933 us; speedup 1.0000x reference)
//
#include <hip/hip_runtime.h>

// QuantumSpectralConv: x[4,128,128,64] f32, W[16,16,64,64,4] re/im planes.
//   x_ft = DFT_{H,W}(x) truncated to 16x16 modes
//   om[b,k,m,o] = sum_{n,c} x_ft[b,k,n,c] * (sum_s W[m,n,c,o,s]) / 2
//   out = Re(iDFT zero-padded)  -> [4,128,128,64] f32
//
// 5-kernel pipeline: dft_w -> dft_h -> gemm3 -> reduce2 -> idft.
// R8 lesson: staging WEIGHTS (reuse=1) through LDS was pure overhead; the
// kernel was 80% stall at 2 waves/SIMD. gemm3 streams weights global->reg
// (contiguous 1KB/wave lines, deep prefetch), keeps xft (reuse=1024) in a
// 16KB LDS slab read via wave-uniform broadcast b128. Split-K x16 with an
// 8.4MB partial buffer + tiny reduce. Schmidt 0.5 folded into idft scale.

static constexpr int BATCH = 4;
static constexpr float STEP_C = 0.9987954562051724f;   // cos(2*pi/128)
static constexpr float STEP_S = 0.04906767432741801f;  // sin(2*pi/128)

// float offsets into workspace (~13.6 MB total)
static constexpr size_t TMP_OFF = 0;          // tmp1: 524288 complex (4.2MB)
static constexpr size_t XFT_OFF = 1048576;    // 65536 complex (0.5MB)
static constexpr size_t OMT_OFF = 1179648;    // 65536 complex (0.5MB)
static constexpr size_t P_OFF   = 1310720;    // 1048576 complex (8.4MB)

__device__ __forceinline__ float2 cmulp(float2 a, float2 b) {  // a*b (+i)
    return make_float2(a.x * b.x - a.y * b.y, a.x * b.y + a.y * b.x);
}

// DFT over W: tmp1[b,h,n,c] = sum_w x[b,h,w,c] * e^{-2pi i n w/128}, n<16
// block per (b,h) = 512 blocks. Thread: one n (tid>>4), 4 c's (tid&15).
__global__ __launch_bounds__(256) void k_dft_w(const float* __restrict__ x,
                                               float2* __restrict__ tmp1) {
    __shared__ float4 xs[2048];                       // [128 w][16 c4] = 32KB
    const int bid = blockIdx.x;                       // b*128 + h
    const float4* x4 = reinterpret_cast<const float4*>(x) + (size_t)bid * 2048;
    #pragma unroll
    for (int i = 0; i < 8; ++i) xs[threadIdx.x + 256 * i] = x4[threadIdx.x + 256 * i];
    const int n  = threadIdx.x >> 4;
    const int c4 = threadIdx.x & 15;
    float rs, rc;                                     // rot = e^{+2pi i n/128}
    sincosf(6.283185307179586f * (float)n * 0.0078125f, &rs, &rc);
    const float2 rot = make_float2(rc, rs);
    __syncthreads();
    float4 ar = make_float4(0.f, 0.f, 0.f, 0.f);
    float4 ai = make_float4(0.f, 0.f, 0.f, 0.f);
    float2 tw = make_float2(1.f, 0.f);                // e^{+2pi i n w/128}
    #pragma unroll 8
    for (int w = 0; w < 128; ++w) {
        const float4 v = xs[w * 16 + c4];
        ar.x += v.x * tw.x; ai.x -= v.x * tw.y;
        ar.y += v.y * tw.x; ai.y -= v.y * tw.y;
        ar.z += v.z * tw.x; ai.z -= v.z * tw.y;
        ar.w += v.w * tw.x; ai.w -= v.w * tw.y;
        tw = cmulp(tw, rot);
    }
    float4* o = reinterpret_cast<float4*>(tmp1 + ((size_t)bid * 16 + n) * 64 + c4 * 4);
    o[0] = make_float4(ar.x, ai.x, ar.y, ai.y);
    o[1] = make_float4(ar.z, ai.z, ar.w, ai.w);
}

// DFT over H: xft[(b*16+k)*1024+n*64+c] = sum_h tmp1[b,h,n,c] e^{-2pi i k h/128}
// grid 512 = (b 4, k 16, nh 8); thread: (hs = tid>>7) h-half, ol = tid&127.
__global__ __launch_bounds__(256) void k_dft_h(const float2* __restrict__ tmp1,
                                               float2* __restrict__ xft) {
    __shared__ float2 red[128];
    const int bid = blockIdx.x;
    const int nh = bid & 7;
    const int k  = (bid >> 3) & 15;
    const int b  = bid >> 7;
    const int ol = threadIdx.x & 127;
    const int hs = threadIdx.x >> 7;
    const int c  = ol & 63;
    const int n  = nh * 2 + (ol >> 6);
    float rs, rc;                                     // rot = e^{+2pi i k/128}
    sincosf(6.283185307179586f * (float)k * 0.0078125f, &rs, &rc);
    const float2 rot = make_float2(rc, rs);
    // start angle: 2pi*k*(hs*64)/128 = pi*k*hs -> (+-1, 0)
    float2 tw = make_float2((hs && (k & 1)) ? -1.f : 1.f, 0.f);
    const float2* src = tmp1 + (size_t)b * 131072 + n * 64 + c + (size_t)hs * 65536;
    float2 acc = make_float2(0.f, 0.f);
    #pragma unroll 8
    for (int j = 0; j < 64; ++j) {
        const float2 a = src[(size_t)j * 1024];
        acc.x += a.x * tw.x + a.y * tw.y;             // conj twiddle: (c-is)
        acc.y += a.y * tw.x - a.x * tw.y;
        tw = cmulp(tw, rot);
    }
    if (hs) red[ol] = acc;
    __syncthreads();
    if (!hs) {
        const float2 r = red[ol];
        acc.x += r.x; acc.y += r.y;
        xft[(size_t)(b * 16 + k) * 1024 + n * 64 + c] = acc;
    }
}

// Complex GEMM, split-K x16 (one n per block), weights streamed from global.
//   grid 512: bid = rh*256 + m*16 + n  (rh-sharers of the weight stream are
//   bid, bid+256 -> same XCD under %8 round-robin). 256 thr = 4 waves.
//   Wave w: local rows 8w..8w+7 (global rows rh*32+...); lane = o.
//   xs[c][row_local] = xft slab (16KB LDS, broadcast b128 reads).
//   NOTE: no 0.5 Schmidt scale here -- folded into k_idft's inv constant.
//   P[n][b][m][o][k] partial (k innermost, float4-storable).
__global__ __launch_bounds__(256) void k_gemm3(const float2* __restrict__ xft,
                                               const float* __restrict__ wr,
                                               const float* __restrict__ wi,
                                               float2* __restrict__ P) {
    __shared__ float2 xs[64 * 32];                    // [c 64][row 32] 16KB
    const int bid = blockIdx.x;
    const int n  = bid & 15;
    const int m  = (bid >> 4) & 15;
    const int rh = bid >> 8;
    {   // stage xft slab: rows rh*32..+31, c 0..63 (transposed into [c][row])
        const int rl = threadIdx.x & 31;
        const int c8 = threadIdx.x >> 5;              // 0..7
        const float4* src = reinterpret_cast<const float4*>(
            xft + (size_t)(rh * 32 + rl) * 1024 + n * 64 + c8 * 8);
        #pragma unroll
        for (int j = 0; j < 4; ++j) {
            const float4 q = src[j];                  // complex c8*8+2j, +1
            xs[(c8 * 8 + 2 * j) * 32 + rl]     = make_float2(q.x, q.y);
            xs[(c8 * 8 + 2 * j + 1) * 32 + rl] = make_float2(q.z, q.w);
        }
    }
    const int o = threadIdx.x & 63;
    const int w = threadIdx.x >> 6;                   // wave: local rows 8w..8w+7
    const float4* wrp = reinterpret_cast<const float4*>(wr) +
                        ((size_t)(m * 16 + n) * 4096 + o);   // + c*64 per step
    const float4* wip = reinterpret_cast<const float4*>(wi) +
                        ((size_t)(m * 16 + n) * 4096 + o);
    float2 acc[8] = {};
    __syncthreads();
    #pragma unroll 8
    for (int c = 0; c < 64; ++c) {
        const float4 a = wrp[(size_t)c * 64];         // wave: 1KB contiguous
        const float4 e = wip[(size_t)c * 64];
        const float bw = (a.x + a.y) + (a.z + a.w);   // sum_s (no 0.5)
        const float bi = (e.x + e.y) + (e.z + e.w);
        #pragma unroll
        for (int j = 0; j < 4; ++j) {                 // rows 8w+2j, +1
            const float4 x2 = *reinterpret_cast<const float4*>(&xs[c * 32 + 8 * w + 2 * j]);
            acc[2 * j].x     += x2.x * bw - x2.y * bi;
            acc[2 * j].y     += x2.x * bi + x2.y * bw;
            acc[2 * j + 1].x += x2.z * bw - x2.w * bi;
            acc[2 * j + 1].y += x2.z * bi + x2.w * bw;
        }
    }
    // rows rh*32+8w..+7 share one b; k0 = start k (even) -> float4 stores
    const int grow0 = rh * 32 + 8 * w;
    const int b = grow0 >> 4, k0 = grow0 & 15;
    float2* dst = P + ((((size_t)n * 4 + b) * 16 + m) * 64 + o) * 16 + k0;
    #pragma unroll
    for (int j = 0; j < 4; ++j)
        *reinterpret_cast<float4*>(&dst[2 * j]) =
            make_float4(acc[2 * j].x, acc[2 * j].y, acc[2 * j + 1].x, acc[2 * j + 1].y);
}

// reduce over the 16 n-partials: omT[i] = sum_n P[n][i]  (i = b,m,o,k flat)
__global__ __launch_bounds__(256) void k_reduce2(const float4* __restrict__ P4,
                                                 float4* __restrict__ om4) {
    const int i = blockIdx.x * 256 + threadIdx.x;     // 32768 float4
    float4 s = make_float4(0.f, 0.f, 0.f, 0.f);
    #pragma unroll
    for (int n = 0; n < 16; ++n) {
        const float4 v = P4[(size_t)n * 32768 + i];
        s.x += v.x; s.y += v.y; s.z += v.z; s.w += v.w;
    }
    om4[i] = s;
}

// Fused inverse: block = (b,h) = 512 blocks.
//   u_s[m][o] = sum_k omT[b][m][o][k] e^{+2pi i k h/128}   (phase 1, LDS)
//   out[b,h,w,o] = (1/32768) * sum_m Re(u_s[m][o] e^{+2pi i m w/128})
//   (1/32768 = 1/16384 iFFT norm x 0.5 Schmidt fold from gemm3)
__global__ __launch_bounds__(256) void k_idft(const float2* __restrict__ omT,
                                              float* __restrict__ out) {
    __shared__ float2 u_s[1024];                      // [m16][o64] 8KB
    const int bid = blockIdx.x;                       // b*128 + h
    const int h = bid & 127, b = bid >> 7;
    float hs_, hc_;                                   // rot_k = e^{+2pi i h/128}
    sincosf(6.283185307179586f * (float)h * 0.0078125f, &hs_, &hc_);
    const float2 rotk = make_float2(hc_, hs_);
    #pragma unroll
    for (int i = 0; i < 4; ++i) {                     // phase 1: 4 u per thread
        const int e = threadIdx.x + 256 * i;          // m*64 + o
        const float4* src = reinterpret_cast<const float4*>(
            omT + (((size_t)b * 16 + (e >> 6)) * 64 + (e & 63)) * 16);
        float re = 0.f, im = 0.f;
        float2 tw = make_float2(1.f, 0.f);            // e^{+2pi i k h/128}
        #pragma unroll
        for (int k8 = 0; k8 < 8; ++k8) {
            const float4 q = src[k8];                 // k = 2k8, 2k8+1
            re += q.x * tw.x - q.y * tw.y; im += q.x * tw.y + q.y * tw.x;
            tw = cmulp(tw, rotk);
            re += q.z * tw.x - q.w * tw.y; im += q.z * tw.y + q.w * tw.x;
            tw = cmulp(tw, rotk);
        }
        u_s[e] = make_float2(re, im);
    }
    __syncthreads();
    const int o4 = threadIdx.x & 15;                  // 4 o's
    const int wg = threadIdx.x >> 4;                  // 8 w's
    float4 va[16], vb[16];                            // u strip in registers
    #pragma unroll
    for (int mm = 0; mm < 16; ++mm) {
        const float4* up = reinterpret_cast<const float4*>(&u_s[mm * 64 + o4 * 4]);
        va[mm] = up[0];                               // complex o4*4+0, +1
        vb[mm] = up[1];                               // complex o4*4+2, +3
    }
    float ws_, wc_;                                   // rot_m = e^{+2pi i w/128}
    sincosf(6.283185307179586f * (float)(wg * 8) * 0.0078125f, &ws_, &wc_);
    float2 rotm = make_float2(wc_, ws_);
    const float2 step = make_float2(STEP_C, STEP_S);  // advance w by 1
    const float inv = 1.0f / 32768.0f;
    #pragma unroll
    for (int i = 0; i < 8; ++i) {
        const int w = wg * 8 + i;
        float4 acc = make_float4(0.f, 0.f, 0.f, 0.f);
        float2 tw = make_float2(1.f, 0.f);            // e^{+2pi i m w/128}
        #pragma unroll
        for (int mm = 0; mm < 16; ++mm) {
            acc.x += va[mm].x * tw.x - va[mm].y * tw.y;
            acc.y += va[mm].z * tw.x - va[mm].w * tw.y;
            acc.z += vb[mm].x * tw.x - vb[mm].y * tw.y;
            acc.w += vb[mm].z * tw.x - vb[mm].w * tw.y;
            tw = cmulp(tw, rotm);
        }
        acc.x *= inv; acc.y *= inv; acc.z *= inv; acc.w *= inv;
        *reinterpret_cast<float4*>(out + ((size_t)bid * 128 + w) * 64 + o4 * 4) = acc;
        rotm = cmulp(rotm, step);
    }
}

extern "C" void kernel_launch(void* const* d_in, const int* in_sizes, int n_in,
                              void* d_out, int out_size, void* d_ws, size_t ws_size,
                              hipStream_t stream) {
    const float* x  = (const float*)d_in[0];
    const float* wr = (const float*)d_in[1];
    const float* wi = (const float*)d_in[2];
    float* out = (float*)d_out;
    float* ws  = (float*)d_ws;

    float2* tmp1 = (float2*)(ws + TMP_OFF);
    float2* xft  = (float2*)(ws + XFT_OFF);
    float2* omT  = (float2*)(ws + OMT_OFF);
    float2* P    = (float2*)(ws + P_OFF);

    k_dft_w  <<<BATCH * 128, 256, 0, stream>>>(x, tmp1);
    k_dft_h  <<<512, 256, 0, stream>>>(tmp1, xft);
    k_gemm3  <<<512, 256, 0, stream>>>(xft, wr, wi, P);
    k_reduce2<<<128, 256, 0, stream>>>((const float4*)P, (float4*)omT);
    k_idft   <<<BATCH * 128, 256, 0, stream>>>(omT, out);
}